// Round 2
// 2096.739 us; speedup vs baseline: 1.2523x; 1.2523x over previous
//
#include <hip/hip_runtime.h>
#include <math.h>
#include <stdint.h>

#define N_NODES 50000
#define N_EDGES 400000
#define N_T 4
#define N_R 8
#define N_H 8
#define DKD 32
#define D 256
#define TM 64
#define N_SEG (N_NODES * N_R)
#define PROJ_BLOCKS ((N_NODES + TM - 1) / TM + N_T)   // 786 >= sum of per-type ceils

typedef __bf16 v8bf __attribute__((ext_vector_type(8)));
typedef float v4f __attribute__((ext_vector_type(4)));
typedef unsigned short u16;

__device__ __forceinline__ u16 f2bf(float f) {
    unsigned int u = __float_as_uint(f);
    u += 0x7fffu + ((u >> 16) & 1u);          // RNE
    return (u16)(u >> 16);
}

// load 32 contiguous bf16 -> 32 floats (4x 16B loads)
__device__ __forceinline__ void load_bf32(const u16* __restrict__ p, float* f) {
    const uint4* p4 = (const uint4*)p;
    #pragma unroll
    for (int j = 0; j < 4; j++) {
        uint4 u = p4[j];
        f[8 * j + 0] = __uint_as_float(u.x << 16);
        f[8 * j + 1] = __uint_as_float(u.x & 0xffff0000u);
        f[8 * j + 2] = __uint_as_float(u.y << 16);
        f[8 * j + 3] = __uint_as_float(u.y & 0xffff0000u);
        f[8 * j + 4] = __uint_as_float(u.z << 16);
        f[8 * j + 5] = __uint_as_float(u.z & 0xffff0000u);
        f[8 * j + 6] = __uint_as_float(u.w << 16);
        f[8 * j + 7] = __uint_as_float(u.w & 0xffff0000u);
    }
}

// dot of 8 bf16 (packed in uint4) with 8 f32
__device__ __forceinline__ float dot8f(uint4 m, const float* v) {
    float s;
    s  = __uint_as_float(m.x << 16)          * v[0];
    s += __uint_as_float(m.x & 0xffff0000u)  * v[1];
    s += __uint_as_float(m.y << 16)          * v[2];
    s += __uint_as_float(m.y & 0xffff0000u)  * v[3];
    s += __uint_as_float(m.z << 16)          * v[4];
    s += __uint_as_float(m.z & 0xffff0000u)  * v[5];
    s += __uint_as_float(m.w << 16)          * v[6];
    s += __uint_as_float(m.w & 0xffff0000u)  * v[7];
    return s;
}

// ---------------- f32 -> bf16 conversion (weights) ----------------
__global__ __launch_bounds__(256) void k_cvt4(const float4* __restrict__ s,
                                              ushort4* __restrict__ d, int n4) {
    int i = blockIdx.x * 256 + threadIdx.x;
    if (i < n4) {
        float4 v = s[i];
        ushort4 o;
        o.x = f2bf(v.x); o.y = f2bf(v.y); o.z = f2bf(v.z); o.w = f2bf(v.w);
        d[i] = o;
    }
}

// rel_msg [mat][d0][f] f32 -> Mt [mat][f][d0] bf16 (per 32x32 matrix transpose)
__global__ __launch_bounds__(256) void k_cvt_t(const float* __restrict__ s,
                                               u16* __restrict__ d) {
    int i = blockIdx.x * 256 + threadIdx.x;
    if (i >= N_R * N_H * DKD * DKD) return;
    int mat = i >> 10, w = i & 1023;
    int d0 = w >> 5, f = w & 31;
    d[(mat << 10) + f * DKD + d0] = f2bf(s[i]);
}

// ---------------- bucketing by node type ----------------
__global__ void k_hist(const int* __restrict__ nt, int* __restrict__ cnt) {
    int n = blockIdx.x * blockDim.x + threadIdx.x;
    if (n < N_NODES) atomicAdd(&cnt[nt[n]], 1);
}

__global__ void k_scan(const int* __restrict__ cnt, int* __restrict__ off,
                       int* __restrict__ toff) {
    int o = 0, to = 0;
    for (int t = 0; t < N_T; t++) {
        off[t] = o; toff[t] = to;
        o += cnt[t]; to += (cnt[t] + TM - 1) / TM;
    }
    off[N_T] = o; toff[N_T] = to;
}

__global__ void k_scatter(const int* __restrict__ nt, const int* __restrict__ off,
                          int* __restrict__ cur, int* __restrict__ order) {
    int n = blockIdx.x * blockDim.x + threadIdx.x;
    if (n >= N_NODES) return;
    int t = nt[n];
    int pos = off[t] + atomicAdd(&cur[t], 1);
    order[pos] = n;
}

// ---------------- segment CSR (seg = dst*R + etype) ----------------
__global__ void k_hist_seg(const int* __restrict__ dst, const int* __restrict__ et,
                           int* __restrict__ cnt) {
    int e = blockIdx.x * blockDim.x + threadIdx.x;
    if (e < N_EDGES) atomicAdd(&cnt[dst[e] * N_R + et[e]], 1);
}

// level 1: per-block (1024) exclusive scan + block sums
__global__ __launch_bounds__(1024) void k_scan_l1(const int* __restrict__ cnt,
                                                  int* __restrict__ excl,
                                                  int* __restrict__ bsum) {
    __shared__ int sh[1024];
    int tid = threadIdx.x, i = blockIdx.x * 1024 + tid;
    int v = (i < N_SEG) ? cnt[i] : 0;
    sh[tid] = v;
    __syncthreads();
    #pragma unroll
    for (int ofs = 1; ofs < 1024; ofs <<= 1) {
        int t = (tid >= ofs) ? sh[tid - ofs] : 0;
        __syncthreads();
        sh[tid] += t;
        __syncthreads();
    }
    if (i < N_SEG) excl[i] = sh[tid] - v;
    if (tid == 1023) bsum[blockIdx.x] = sh[1023];
}

// level 2: single block exclusive scan of block sums (NB <= 512)
__global__ __launch_bounds__(512) void k_scan_l2(int* __restrict__ bsum, int NB) {
    __shared__ int sh[512];
    int tid = threadIdx.x;
    int v = (tid < NB) ? bsum[tid] : 0;
    sh[tid] = v;
    __syncthreads();
    #pragma unroll
    for (int ofs = 1; ofs < 512; ofs <<= 1) {
        int t = (tid >= ofs) ? sh[tid - ofs] : 0;
        __syncthreads();
        sh[tid] += t;
        __syncthreads();
    }
    if (tid < NB) bsum[tid] = sh[tid] - v;
}

// level 3: add block offsets, set final rowptr entry
__global__ void k_scan_l3(int* __restrict__ excl, const int* __restrict__ bsum) {
    int i = blockIdx.x * blockDim.x + threadIdx.x;
    if (i < N_SEG) excl[i] += bsum[i >> 10];
    else if (i == N_SEG) excl[N_SEG] = N_EDGES;
}

// scatter src node id directly (fused kernel never needs the edge id)
__global__ void k_scatter_seg(const int* __restrict__ src, const int* __restrict__ dst,
                              const int* __restrict__ et, const int* __restrict__ rp,
                              int* __restrict__ cur, int* __restrict__ esrc) {
    int e = blockIdx.x * blockDim.x + threadIdx.x;
    if (e >= N_EDGES) return;
    int sg = dst[e] * N_R + et[e];
    int pos = rp[sg] + atomicAdd(&cur[sg], 1);
    esrc[pos] = src[e];
}

// ---------------- fused typed K/Q/V projection (MFMA) ----------------
__global__ __launch_bounds__(256) void k_proj(
    const float* __restrict__ x, const int* __restrict__ order,
    const int* __restrict__ off, const int* __restrict__ toff,
    const u16* __restrict__ Wkb, const float* __restrict__ bk,
    const u16* __restrict__ Wqb, const float* __restrict__ bq,
    const u16* __restrict__ Wvb, const float* __restrict__ bv,
    u16* __restrict__ Kb, u16* __restrict__ Qb, u16* __restrict__ Vb) {
    __shared__ __align__(16) u16 xs[TM][D + 8];
    int b = blockIdx.x;
    int t = -1;
    #pragma unroll
    for (int i = 0; i < N_T; i++)
        if (b >= toff[i] && b < toff[i + 1]) t = i;
    if (t < 0) return;
    int nodeBase = off[t] + (b - toff[t]) * TM;
    int count = min(TM, off[t + 1] - nodeBase);
    int tid = threadIdx.x;

    for (int j = tid; j < TM * (D / 4); j += 256) {
        int row = j >> 6, ch = j & 63;
        float4 v = {0.f, 0.f, 0.f, 0.f};
        if (row < count) {
            int g = order[nodeBase + row];
            v = *(const float4*)(x + (size_t)g * D + ch * 4);
        }
        ushort4 o;
        o.x = f2bf(v.x); o.y = f2bf(v.y); o.z = f2bf(v.z); o.w = f2bf(v.w);
        *(ushort4*)&xs[row][ch * 4] = o;
    }
    __syncthreads();

    int lane = tid & 63, wave = tid >> 6;
    int m = lane & 15, quad = lane >> 4;
    v8bf a[8];
    #pragma unroll
    for (int ks = 0; ks < 8; ks++)
        a[ks] = *(const v8bf*)&xs[wave * 16 + m][ks * 32 + quad * 8];

    int grow[4]; bool vrow[4];
    #pragma unroll
    for (int r = 0; r < 4; r++) {
        int rowi = wave * 16 + quad * 4 + r;
        vrow[r] = (rowi < count);
        grow[r] = vrow[r] ? order[nodeBase + rowi] : 0;
    }

    const u16* Ws[3] = {Wkb + (size_t)t * D * D, Wqb + (size_t)t * D * D, Wvb + (size_t)t * D * D};
    const float* Bs[3] = {bk + t * D, bq + t * D, bv + t * D};
    u16* Os[3] = {Kb, Qb, Vb};

    for (int p = 0; p < 3; p++) {
        const u16* W = Ws[p];
        for (int dt = 0; dt < 16; dt++) {
            int dcol = dt * 16 + m;
            v4f acc = {0.f, 0.f, 0.f, 0.f};
            #pragma unroll
            for (int ks = 0; ks < 8; ks++) {
                v8bf bf = *(const v8bf*)(W + (size_t)dcol * D + ks * 32 + quad * 8);
                acc = __builtin_amdgcn_mfma_f32_16x16x32_bf16(a[ks], bf, acc, 0, 0, 0);
            }
            float bias = Bs[p][dcol];
            #pragma unroll
            for (int r = 0; r < 4; r++) {
                if (vrow[r])
                    Os[p][(size_t)grow[r] * D + dcol] = f2bf(acc[r] + bias);
            }
        }
    }
}

// ---------------- fused attention + softmax + aggregation + msg transform ----
// one wave per dst node; lane = h*8 + fl owns head h, feature slice [fl*4, fl*4+4)
// Per node n:  for each present r:
//   qtilde = A_r @ q[n]           (once per (n,r), not per edge)
//   for e in seg(n,r): att = k_src . qtilde ; ex = exp(att*pri/sqrt(dk))
//                      den += ex ; U += ex * v_src        (raw V, 4 FMA/lane)
//   msg += M_r @ (U/den)          (once per (n,r))
// out = msg / |present| -> TBF (bf16). TBF aliases Qb: each wave reads only its
// own Q row before writing only its own TBF row -> race-free.
__global__ __launch_bounds__(256) void k_fused(
    const u16* __restrict__ Kb, u16* QTb, const u16* __restrict__ Vb,
    const int* __restrict__ rowptr, const int* __restrict__ esrc,
    const u16* __restrict__ Ab, const u16* __restrict__ Mtb,
    const float* __restrict__ pri) {
    __shared__ __align__(16) float Uld[4][N_H][40];   // 5.1 KB, pad 40 to dodge banks
    int wave = threadIdx.x >> 6, lane = threadIdx.x & 63;
    int n = blockIdx.x * 4 + wave;
    if (n >= N_NODES) return;
    int h = lane >> 3, fo = (lane & 7) * 4;
    int base = n * N_R;

    float qv[32];
    load_bf32(QTb + (size_t)n * D + h * DKD, qv);   // 64B, shared across head group via L1

    float macc[4] = {0.f, 0.f, 0.f, 0.f};
    int np = 0;

    #pragma unroll
    for (int r = 0; r < N_R; r++) {
        int s0 = rowptr[base + r], s1 = rowptr[base + r + 1];
        if (s0 >= s1) continue;
        np++;

        // qtilde[fo+i] = sum_f A[r][h][fo+i][f] * q[f]   (A rows are contiguous)
        const u16* Ar = Ab + ((size_t)(r * N_H + h) * DKD + fo) * DKD;
        float qtv[4];
        #pragma unroll
        for (int i = 0; i < 4; i++) {
            const uint4* ar = (const uint4*)(Ar + i * DKD);
            qtv[i] = dot8f(ar[0], qv) + dot8f(ar[1], qv + 8)
                   + dot8f(ar[2], qv + 16) + dot8f(ar[3], qv + 24);
        }
        float scale = pri[r * N_H + h] * 0.17677669529663687f;   // 1/sqrt(32)

        float dtmp = 0.f, u0 = 0.f, u1 = 0.f, u2 = 0.f, u3 = 0.f;
        for (int ei = s0; ei < s1; ei++) {
            int s = esrc[ei];                                // wave-uniform
            uint2 ku = *(const uint2*)(Kb + (size_t)s * D + h * DKD + fo);
            uint2 vu = *(const uint2*)(Vb + (size_t)s * D + h * DKD + fo);
            float p = __uint_as_float(ku.x << 16)         * qtv[0]
                    + __uint_as_float(ku.x & 0xffff0000u) * qtv[1]
                    + __uint_as_float(ku.y << 16)         * qtv[2]
                    + __uint_as_float(ku.y & 0xffff0000u) * qtv[3];
            p += __shfl_xor(p, 1);
            p += __shfl_xor(p, 2);
            p += __shfl_xor(p, 4);                            // full 32-d dot in all 8 lanes
            float ex = __expf(p * scale);
            dtmp += ex;
            u0 += ex * __uint_as_float(vu.x << 16);
            u1 += ex * __uint_as_float(vu.x & 0xffff0000u);
            u2 += ex * __uint_as_float(vu.y << 16);
            u3 += ex * __uint_as_float(vu.y & 0xffff0000u);
        }

        float invd = 1.f / dtmp;
        float4 uw = {u0 * invd, u1 * invd, u2 * invd, u3 * invd};
        __builtin_amdgcn_wave_barrier();
        *(float4*)&Uld[wave][h][fo] = uw;                     // wave-private scratch
        __builtin_amdgcn_wave_barrier();

        float Uv[32];
        #pragma unroll
        for (int i = 0; i < 8; i++)
            *(float4*)&Uv[4 * i] = *(const float4*)&Uld[wave][h][4 * i];

        // macc[j] += sum_d Mt[r][h][fo+j][d] * U[h][d]
        const u16* mp = Mtb + ((size_t)(r * N_H + h) * DKD + fo) * DKD;
        #pragma unroll
        for (int j = 0; j < 4; j++) {
            const uint4* mr = (const uint4*)(mp + j * DKD);
            macc[j] += dot8f(mr[0], Uv) + dot8f(mr[1], Uv + 8)
                     + dot8f(mr[2], Uv + 16) + dot8f(mr[3], Uv + 24);
        }
        __builtin_amdgcn_wave_barrier();
    }

    float invp = (np > 0) ? 1.f / (float)np : 1.f;
    ushort4 o;
    o.x = f2bf(macc[0] * invp); o.y = f2bf(macc[1] * invp);
    o.z = f2bf(macc[2] * invp); o.w = f2bf(macc[3] * invp);
    *(ushort4*)(QTb + (size_t)n * D + h * DKD + fo) = o;
}

// ---------------- typed output linear + sigmoid-skip blend (MFMA) ----------------
__global__ __launch_bounds__(256) void k_out(
    const u16* __restrict__ TBF, const float* __restrict__ x,
    const int* __restrict__ order, const int* __restrict__ off, const int* __restrict__ toff,
    const u16* __restrict__ Wab, const float* __restrict__ ba,
    const float* __restrict__ skip, float* __restrict__ out) {
    __shared__ __align__(16) u16 xs[TM][D + 8];
    int b = blockIdx.x;
    int t = -1;
    #pragma unroll
    for (int i = 0; i < N_T; i++)
        if (b >= toff[i] && b < toff[i + 1]) t = i;
    if (t < 0) return;
    int nodeBase = off[t] + (b - toff[t]) * TM;
    int count = min(TM, off[t + 1] - nodeBase);
    int tid = threadIdx.x;

    for (int j = tid; j < TM * 32; j += 256) {
        int row = j >> 5, ch = j & 31;
        ushort4 z = {0, 0, 0, 0};
        if (row < count) {
            int g = order[nodeBase + row];
            const ushort4* p = (const ushort4*)(TBF + (size_t)g * D + ch * 8);
            *(ushort4*)&xs[row][ch * 8] = p[0];
            *(ushort4*)&xs[row][ch * 8 + 4] = p[1];
        } else {
            *(ushort4*)&xs[row][ch * 8] = z;
            *(ushort4*)&xs[row][ch * 8 + 4] = z;
        }
    }
    __syncthreads();

    int lane = tid & 63, wave = tid >> 6;
    int m = lane & 15, quad = lane >> 4;
    v8bf a[8];
    #pragma unroll
    for (int ks = 0; ks < 8; ks++)
        a[ks] = *(const v8bf*)&xs[wave * 16 + m][ks * 32 + quad * 8];

    int grow[4]; bool vrow[4];
    #pragma unroll
    for (int r = 0; r < 4; r++) {
        int rowi = wave * 16 + quad * 4 + r;
        vrow[r] = (rowi < count);
        grow[r] = vrow[r] ? order[nodeBase + rowi] : 0;
    }

    float sv = skip[t];
    float alpha = 1.f / (1.f + __expf(-sv));
    float beta = 1.f - alpha;
    const u16* W = Wab + (size_t)t * D * D;

    for (int dt = 0; dt < 16; dt++) {
        int dcol = dt * 16 + m;
        v4f acc = {0.f, 0.f, 0.f, 0.f};
        #pragma unroll
        for (int ks = 0; ks < 8; ks++) {
            v8bf bf = *(const v8bf*)(W + (size_t)dcol * D + ks * 32 + quad * 8);
            acc = __builtin_amdgcn_mfma_f32_16x16x32_bf16(a[ks], bf, acc, 0, 0, 0);
        }
        float bias = ba[t * D + dcol];
        #pragma unroll
        for (int r = 0; r < 4; r++) {
            if (vrow[r]) {
                size_t o = (size_t)grow[r] * D + dcol;
                out[o] = alpha * (acc[r] + bias) + beta * x[o];
            }
        }
    }
}

// ---------------- launch ----------------
extern "C" void kernel_launch(void* const* d_in, const int* in_sizes, int n_in,
                              void* d_out, int out_size, void* d_ws, size_t ws_size,
                              hipStream_t stream) {
    const float* x       = (const float*)d_in[0];
    const int* node_type = (const int*)d_in[1];
    const int* src       = (const int*)d_in[2];
    const int* dst       = (const int*)d_in[3];
    const int* etype     = (const int*)d_in[4];
    const float* Wk = (const float*)d_in[5];
    const float* bk = (const float*)d_in[6];
    const float* Wq = (const float*)d_in[7];
    const float* bq = (const float*)d_in[8];
    const float* Wv = (const float*)d_in[9];
    const float* bv = (const float*)d_in[10];
    const float* Wa = (const float*)d_in[11];
    const float* ba = (const float*)d_in[12];
    const float* rel_pri = (const float*)d_in[13];
    const float* rel_att = (const float*)d_in[14];
    const float* rel_msg = (const float*)d_in[15];
    const float* skip    = (const float*)d_in[16];
    float* out = (float*)d_out;
    char* ws = (char*)d_ws;

    // ws (~79.7 MB, unchanged footprint): Kb | Qb | Vb (bf16 node tensors),
    // bf16 weights, order, counters. TBF aliases Qb (per-row read-then-write
    // by the same wave in k_fused -> race-free).
    const size_t SZH = (size_t)N_NODES * D * 2;          // 25.6 MB
    const size_t WSZ = (size_t)N_T * D * D;              // 262144 elems
    const size_t RSZ = (size_t)N_R * N_H * DKD * DKD;    // 65536 elems
    u16* Kb  = (u16*)(ws);
    u16* Qb  = (u16*)(ws + SZH);
    u16* Vb  = (u16*)(ws + 2 * SZH);
    u16* TBF = Qb;                              // aliases Qb
    u16* Wkb = (u16*)(ws + 3 * SZH);
    u16* Wqb = Wkb + WSZ;
    u16* Wvb = Wqb + WSZ;
    u16* Wab = Wvb + WSZ;
    u16* Ab  = Wab + WSZ;
    u16* Mtb = Ab + RSZ;
    int* order = (int*)(Mtb + RSZ);
    int* small = order + N_NODES;
    int* cnt  = small;        // 4
    int* cur  = small + 4;    // 4
    int* offp = small + 8;    // 5
    int* toffp= small + 13;   // 5

    // d_out as scratch (all dead before k_out rewrites it):
    //   rowptr_seg[S+1] | cnt_seg[S] | cur_seg[S] | esrc[E] | bsum — ~6.4 MB of 51.2 MB
    char* ob = (char*)d_out;
    int* rowptr_seg = (int*)ob;                          // 400001
    int* cnt_seg    = rowptr_seg + (N_SEG + 16);         // 400000
    int* cur_seg    = cnt_seg + N_SEG;                   // 400000 (contiguous w/ cnt)
    int* esrc       = cur_seg + N_SEG;                   // 400000
    int* bsum       = esrc + N_EDGES;                    // 391 (+pad)

    hipMemsetAsync(small, 0, 8 * sizeof(int), stream);
    hipMemsetAsync(cnt_seg, 0, 2 * (size_t)N_SEG * sizeof(int), stream);

    // weight conversions
    k_cvt4<<<(WSZ / 4 + 255) / 256, 256, 0, stream>>>((const float4*)Wk, (ushort4*)Wkb, WSZ / 4);
    k_cvt4<<<(WSZ / 4 + 255) / 256, 256, 0, stream>>>((const float4*)Wq, (ushort4*)Wqb, WSZ / 4);
    k_cvt4<<<(WSZ / 4 + 255) / 256, 256, 0, stream>>>((const float4*)Wv, (ushort4*)Wvb, WSZ / 4);
    k_cvt4<<<(WSZ / 4 + 255) / 256, 256, 0, stream>>>((const float4*)Wa, (ushort4*)Wab, WSZ / 4);
    k_cvt4<<<(RSZ / 4 + 255) / 256, 256, 0, stream>>>((const float4*)rel_att, (ushort4*)Ab, RSZ / 4);
    k_cvt_t<<<(RSZ + 255) / 256, 256, 0, stream>>>(rel_msg, Mtb);

    // node-type buckets
    k_hist<<<(N_NODES + 255) / 256, 256, 0, stream>>>(node_type, cnt);
    k_scan<<<1, 1, 0, stream>>>(cnt, offp, toffp);
    k_scatter<<<(N_NODES + 255) / 256, 256, 0, stream>>>(node_type, offp, cur, order);

    // segment CSR (dst*R + etype)
    const int NB = (N_SEG + 1023) / 1024;                // 391
    k_hist_seg<<<(N_EDGES + 255) / 256, 256, 0, stream>>>(dst, etype, cnt_seg);
    k_scan_l1<<<NB, 1024, 0, stream>>>(cnt_seg, rowptr_seg, bsum);
    k_scan_l2<<<1, 512, 0, stream>>>(bsum, NB);
    k_scan_l3<<<(N_SEG + 1 + 255) / 256, 256, 0, stream>>>(rowptr_seg, bsum);
    k_scatter_seg<<<(N_EDGES + 255) / 256, 256, 0, stream>>>(src, dst, etype,
                                                             rowptr_seg, cur_seg, esrc);

    k_proj<<<PROJ_BLOCKS, 256, 0, stream>>>(x, order, offp, toffp,
                                            Wkb, bk, Wqb, bq, Wvb, bv, Kb, Qb, Vb);

    k_fused<<<(N_NODES + 3) / 4, 256, 0, stream>>>(Kb, Qb, Vb, rowptr_seg, esrc,
                                                   Ab, Mtb, rel_pri);

    k_out<<<PROJ_BLOCKS, 256, 0, stream>>>(TBF, x, order, offp, toffp,
                                           Wab, ba, skip, out);
}

// Round 3
// 2020.073 us; speedup vs baseline: 1.2999x; 1.0380x over previous
//
#include <hip/hip_runtime.h>
#include <math.h>
#include <stdint.h>

#define N_NODES 50000
#define N_EDGES 400000
#define N_T 4
#define N_R 8
#define N_H 8
#define DKD 32
#define D 256
#define TM 64
#define N_SEG (N_NODES * N_R)
#define EMASK 0xFFFFF
#define PROJ_BLOCKS ((N_NODES + TM - 1) / TM + N_T)   // 786 >= sum of per-type ceils

typedef __bf16 v8bf __attribute__((ext_vector_type(8)));
typedef float v4f __attribute__((ext_vector_type(4)));
typedef unsigned short u16;

__device__ __forceinline__ u16 f2bf(float f) {
    unsigned int u = __float_as_uint(f);
    u += 0x7fffu + ((u >> 16) & 1u);          // RNE
    return (u16)(u >> 16);
}

// load 32 contiguous bf16 -> 32 floats (4x 16B loads)
__device__ __forceinline__ void load_bf32(const u16* __restrict__ p, float* f) {
    const uint4* p4 = (const uint4*)p;
    #pragma unroll
    for (int j = 0; j < 4; j++) {
        uint4 u = p4[j];
        f[8 * j + 0] = __uint_as_float(u.x << 16);
        f[8 * j + 1] = __uint_as_float(u.x & 0xffff0000u);
        f[8 * j + 2] = __uint_as_float(u.y << 16);
        f[8 * j + 3] = __uint_as_float(u.y & 0xffff0000u);
        f[8 * j + 4] = __uint_as_float(u.z << 16);
        f[8 * j + 5] = __uint_as_float(u.z & 0xffff0000u);
        f[8 * j + 6] = __uint_as_float(u.w << 16);
        f[8 * j + 7] = __uint_as_float(u.w & 0xffff0000u);
    }
}

// dot of 8 bf16 (packed in uint4) with 8 f32
__device__ __forceinline__ float dot8f(uint4 m, const float* v) {
    float s;
    s  = __uint_as_float(m.x << 16)          * v[0];
    s += __uint_as_float(m.x & 0xffff0000u)  * v[1];
    s += __uint_as_float(m.y << 16)          * v[2];
    s += __uint_as_float(m.y & 0xffff0000u)  * v[3];
    s += __uint_as_float(m.z << 16)          * v[4];
    s += __uint_as_float(m.z & 0xffff0000u)  * v[5];
    s += __uint_as_float(m.w << 16)          * v[6];
    s += __uint_as_float(m.w & 0xffff0000u)  * v[7];
    return s;
}

// ---------------- f32 -> bf16 conversion (weights) ----------------
__global__ __launch_bounds__(256) void k_cvt4(const float4* __restrict__ s,
                                              ushort4* __restrict__ d, int n4) {
    int i = blockIdx.x * 256 + threadIdx.x;
    if (i < n4) {
        float4 v = s[i];
        ushort4 o;
        o.x = f2bf(v.x); o.y = f2bf(v.y); o.z = f2bf(v.z); o.w = f2bf(v.w);
        d[i] = o;
    }
}

// rel_msg [mat][d0][f] f32 -> Mt [mat][f][d0] bf16 (per 32x32 matrix transpose)
__global__ __launch_bounds__(256) void k_cvt_t(const float* __restrict__ s,
                                               u16* __restrict__ d) {
    int i = blockIdx.x * 256 + threadIdx.x;
    if (i >= N_R * N_H * DKD * DKD) return;
    int mat = i >> 10, w = i & 1023;
    int d0 = w >> 5, f = w & 31;
    d[(mat << 10) + f * DKD + d0] = f2bf(s[i]);
}

// ---------------- bucketing by node type ----------------
__global__ void k_hist(const int* __restrict__ nt, int* __restrict__ cnt) {
    int n = blockIdx.x * blockDim.x + threadIdx.x;
    if (n < N_NODES) atomicAdd(&cnt[nt[n]], 1);
}

__global__ void k_scan(const int* __restrict__ cnt, int* __restrict__ off,
                       int* __restrict__ toff) {
    int o = 0, to = 0;
    for (int t = 0; t < N_T; t++) {
        off[t] = o; toff[t] = to;
        o += cnt[t]; to += (cnt[t] + TM - 1) / TM;
    }
    off[N_T] = o; toff[N_T] = to;
}

__global__ void k_scatter(const int* __restrict__ nt, const int* __restrict__ off,
                          int* __restrict__ cur, int* __restrict__ order) {
    int n = blockIdx.x * blockDim.x + threadIdx.x;
    if (n >= N_NODES) return;
    int t = nt[n];
    int pos = off[t] + atomicAdd(&cur[t], 1);
    order[pos] = n;
}

// ---------------- segment CSR (seg = dst*R + etype) ----------------
__global__ void k_hist_seg(const int* __restrict__ dst, const int* __restrict__ et,
                           int* __restrict__ cnt) {
    int e = blockIdx.x * blockDim.x + threadIdx.x;
    if (e < N_EDGES) atomicAdd(&cnt[dst[e] * N_R + et[e]], 1);
}

// level 1: per-block (1024) exclusive scan + block sums
__global__ __launch_bounds__(1024) void k_scan_l1(const int* __restrict__ cnt,
                                                  int* __restrict__ excl,
                                                  int* __restrict__ bsum) {
    __shared__ int sh[1024];
    int tid = threadIdx.x, i = blockIdx.x * 1024 + tid;
    int v = (i < N_SEG) ? cnt[i] : 0;
    sh[tid] = v;
    __syncthreads();
    #pragma unroll
    for (int ofs = 1; ofs < 1024; ofs <<= 1) {
        int t = (tid >= ofs) ? sh[tid - ofs] : 0;
        __syncthreads();
        sh[tid] += t;
        __syncthreads();
    }
    if (i < N_SEG) excl[i] = sh[tid] - v;
    if (tid == 1023) bsum[blockIdx.x] = sh[1023];
}

// level 2: single block exclusive scan of block sums (NB <= 512)
__global__ __launch_bounds__(512) void k_scan_l2(int* __restrict__ bsum, int NB) {
    __shared__ int sh[512];
    int tid = threadIdx.x;
    int v = (tid < NB) ? bsum[tid] : 0;
    sh[tid] = v;
    __syncthreads();
    #pragma unroll
    for (int ofs = 1; ofs < 512; ofs <<= 1) {
        int t = (tid >= ofs) ? sh[tid - ofs] : 0;
        __syncthreads();
        sh[tid] += t;
        __syncthreads();
    }
    if (tid < NB) bsum[tid] = sh[tid] - v;
}

// level 3: add block offsets, set final rowptr entry
__global__ void k_scan_l3(int* __restrict__ excl, const int* __restrict__ bsum) {
    int i = blockIdx.x * blockDim.x + threadIdx.x;
    if (i < N_SEG) excl[i] += bsum[i >> 10];
    else if (i == N_SEG) excl[N_SEG] = N_EDGES;
}

// scatter packed (etype<<20 | src) — fused kernel consumes mixed-r edge stream
__global__ void k_scatter_seg(const int* __restrict__ src, const int* __restrict__ dst,
                              const int* __restrict__ et, const int* __restrict__ rp,
                              int* __restrict__ cur, int* __restrict__ esrc) {
    int e = blockIdx.x * blockDim.x + threadIdx.x;
    if (e >= N_EDGES) return;
    int r = et[e];
    int sg = dst[e] * N_R + r;
    int pos = rp[sg] + atomicAdd(&cur[sg], 1);
    esrc[pos] = src[e] | (r << 20);
}

// ---------------- fused typed K/Q/V projection (MFMA) ----------------
__global__ __launch_bounds__(256) void k_proj(
    const float* __restrict__ x, const int* __restrict__ order,
    const int* __restrict__ off, const int* __restrict__ toff,
    const u16* __restrict__ Wkb, const float* __restrict__ bk,
    const u16* __restrict__ Wqb, const float* __restrict__ bq,
    const u16* __restrict__ Wvb, const float* __restrict__ bv,
    u16* __restrict__ Kb, u16* __restrict__ Qb, u16* __restrict__ Vb) {
    __shared__ __align__(16) u16 xs[TM][D + 8];
    int b = blockIdx.x;
    int t = -1;
    #pragma unroll
    for (int i = 0; i < N_T; i++)
        if (b >= toff[i] && b < toff[i + 1]) t = i;
    if (t < 0) return;
    int nodeBase = off[t] + (b - toff[t]) * TM;
    int count = min(TM, off[t + 1] - nodeBase);
    int tid = threadIdx.x;

    for (int j = tid; j < TM * (D / 4); j += 256) {
        int row = j >> 6, ch = j & 63;
        float4 v = {0.f, 0.f, 0.f, 0.f};
        if (row < count) {
            int g = order[nodeBase + row];
            v = *(const float4*)(x + (size_t)g * D + ch * 4);
        }
        ushort4 o;
        o.x = f2bf(v.x); o.y = f2bf(v.y); o.z = f2bf(v.z); o.w = f2bf(v.w);
        *(ushort4*)&xs[row][ch * 4] = o;
    }
    __syncthreads();

    int lane = tid & 63, wave = tid >> 6;
    int m = lane & 15, quad = lane >> 4;
    v8bf a[8];
    #pragma unroll
    for (int ks = 0; ks < 8; ks++)
        a[ks] = *(const v8bf*)&xs[wave * 16 + m][ks * 32 + quad * 8];

    int grow[4]; bool vrow[4];
    #pragma unroll
    for (int r = 0; r < 4; r++) {
        int rowi = wave * 16 + quad * 4 + r;
        vrow[r] = (rowi < count);
        grow[r] = vrow[r] ? order[nodeBase + rowi] : 0;
    }

    const u16* Ws[3] = {Wkb + (size_t)t * D * D, Wqb + (size_t)t * D * D, Wvb + (size_t)t * D * D};
    const float* Bs[3] = {bk + t * D, bq + t * D, bv + t * D};
    u16* Os[3] = {Kb, Qb, Vb};

    for (int p = 0; p < 3; p++) {
        const u16* W = Ws[p];
        for (int dt = 0; dt < 16; dt++) {
            int dcol = dt * 16 + m;
            v4f acc = {0.f, 0.f, 0.f, 0.f};
            #pragma unroll
            for (int ks = 0; ks < 8; ks++) {
                v8bf bf = *(const v8bf*)(W + (size_t)dcol * D + ks * 32 + quad * 8);
                acc = __builtin_amdgcn_mfma_f32_16x16x32_bf16(a[ks], bf, acc, 0, 0, 0);
            }
            float bias = Bs[p][dcol];
            #pragma unroll
            for (int r = 0; r < 4; r++) {
                if (vrow[r])
                    Os[p][(size_t)grow[r] * D + dcol] = f2bf(acc[r] + bias);
            }
        }
    }
}

// ---------------- fused attention + softmax + aggregation + msg transform ----
// One wave per dst node; lane = h*8 + fl owns head h, feature slice [fl*4,fl*4+4).
// Restructured for MLP: (A) all present qtilde -> registers qt[8][4] (scale
// folded); (B) single mixed-r edge stream, 4 edges per iteration, 8 global
// loads in flight, register accumulators den[8]/ua[8][4] selected by a
// scalar-uniform switch; (C) per present r: normalize, M-transform.
__global__ __launch_bounds__(256) void k_fused(
    const u16* __restrict__ Kb, u16* QTb, const u16* __restrict__ Vb,
    const int* __restrict__ rowptr, const int* __restrict__ esrc,
    const u16* __restrict__ Ab, const u16* __restrict__ Mtb,
    const float* __restrict__ pri) {
    __shared__ __align__(16) float Uld[4][N_H][40];   // 5.1 KB
    int wave = threadIdx.x >> 6, lane = threadIdx.x & 63;
    int n = blockIdx.x * 4 + wave;
    if (n >= N_NODES) return;
    int h = lane >> 3, fo = (lane & 7) * 4;
    int base = n * N_R;

    int bnd[N_R + 1];
    #pragma unroll
    for (int i = 0; i <= N_R; i++) bnd[i] = rowptr[base + i];

    float qv[32];
    load_bf32(QTb + (size_t)n * D + h * DKD, qv);

    // ---- phase A: qtilde for all present r (scale folded in) ----
    float qt[N_R][4];
    int np = 0;
    #pragma unroll
    for (int r = 0; r < N_R; r++) {
        if (bnd[r] >= bnd[r + 1]) continue;
        np++;
        const u16* Ar = Ab + ((size_t)(r * N_H + h) * DKD + fo) * DKD;
        float scale = pri[r * N_H + h] * 0.17677669529663687f;   // 1/sqrt(32)
        #pragma unroll
        for (int i = 0; i < 4; i++) {
            const uint4* ar = (const uint4*)(Ar + i * DKD);
            qt[r][i] = scale * (dot8f(ar[0], qv) + dot8f(ar[1], qv + 8)
                     + dot8f(ar[2], qv + 16) + dot8f(ar[3], qv + 24));
        }
    }

    // ---- phase B: mixed-r edge stream, 4-wide batches ----
    float den[N_R] = {0.f, 0.f, 0.f, 0.f, 0.f, 0.f, 0.f, 0.f};
    float ua[N_R][4] = {};

#define DOTQ(P, RS, KU) { \
    float _k0 = __uint_as_float((KU).x << 16); \
    float _k1 = __uint_as_float((KU).x & 0xffff0000u); \
    float _k2 = __uint_as_float((KU).y << 16); \
    float _k3 = __uint_as_float((KU).y & 0xffff0000u); \
    switch (RS) { \
    case 0: P = _k0*qt[0][0]+_k1*qt[0][1]+_k2*qt[0][2]+_k3*qt[0][3]; break; \
    case 1: P = _k0*qt[1][0]+_k1*qt[1][1]+_k2*qt[1][2]+_k3*qt[1][3]; break; \
    case 2: P = _k0*qt[2][0]+_k1*qt[2][1]+_k2*qt[2][2]+_k3*qt[2][3]; break; \
    case 3: P = _k0*qt[3][0]+_k1*qt[3][1]+_k2*qt[3][2]+_k3*qt[3][3]; break; \
    case 4: P = _k0*qt[4][0]+_k1*qt[4][1]+_k2*qt[4][2]+_k3*qt[4][3]; break; \
    case 5: P = _k0*qt[5][0]+_k1*qt[5][1]+_k2*qt[5][2]+_k3*qt[5][3]; break; \
    case 6: P = _k0*qt[6][0]+_k1*qt[6][1]+_k2*qt[6][2]+_k3*qt[6][3]; break; \
    default: P = _k0*qt[7][0]+_k1*qt[7][1]+_k2*qt[7][2]+_k3*qt[7][3]; break; } }

#define ACCR(R, EX, V0, V1, V2, V3) \
    den[R] += EX; ua[R][0] += EX*V0; ua[R][1] += EX*V1; ua[R][2] += EX*V2; ua[R][3] += EX*V3;

#define ACCE(RS, EX, VU) { \
    float _v0 = __uint_as_float((VU).x << 16); \
    float _v1 = __uint_as_float((VU).x & 0xffff0000u); \
    float _v2 = __uint_as_float((VU).y << 16); \
    float _v3 = __uint_as_float((VU).y & 0xffff0000u); \
    switch (RS) { \
    case 0: ACCR(0, EX, _v0, _v1, _v2, _v3) break; \
    case 1: ACCR(1, EX, _v0, _v1, _v2, _v3) break; \
    case 2: ACCR(2, EX, _v0, _v1, _v2, _v3) break; \
    case 3: ACCR(3, EX, _v0, _v1, _v2, _v3) break; \
    case 4: ACCR(4, EX, _v0, _v1, _v2, _v3) break; \
    case 5: ACCR(5, EX, _v0, _v1, _v2, _v3) break; \
    case 6: ACCR(6, EX, _v0, _v1, _v2, _v3) break; \
    default: ACCR(7, EX, _v0, _v1, _v2, _v3) break; } }

    int eb = bnd[0], ee = bnd[N_R];
    size_t hoff = (size_t)(h * DKD + fo);
    for (int w0 = eb; w0 < ee; w0 += 64) {
        int wcnt = min(64, ee - w0);
        int myek = (lane < wcnt) ? esrc[w0 + lane] : 0;
        for (int i0 = 0; i0 < wcnt; i0 += 4) {
            int mc = wcnt - i0;
            int pk0 = __shfl(myek, i0);
            int pk1 = __shfl(myek, i0 + (mc > 1 ? 1 : 0));
            int pk2 = __shfl(myek, i0 + (mc > 2 ? 2 : 0));
            int pk3 = __shfl(myek, i0 + (mc > 3 ? 3 : 0));
            int s0 = pk0 & EMASK, s1 = pk1 & EMASK, s2 = pk2 & EMASK, s3 = pk3 & EMASK;
            int r0 = __builtin_amdgcn_readfirstlane(pk0) >> 20;
            int r1 = __builtin_amdgcn_readfirstlane(pk1) >> 20;
            int r2 = __builtin_amdgcn_readfirstlane(pk2) >> 20;
            int r3 = __builtin_amdgcn_readfirstlane(pk3) >> 20;
            // issue all 8 loads up front (independent -> MLP)
            uint2 ku0 = *(const uint2*)(Kb + (size_t)s0 * D + hoff);
            uint2 ku1 = *(const uint2*)(Kb + (size_t)s1 * D + hoff);
            uint2 ku2 = *(const uint2*)(Kb + (size_t)s2 * D + hoff);
            uint2 ku3 = *(const uint2*)(Kb + (size_t)s3 * D + hoff);
            uint2 vu0 = *(const uint2*)(Vb + (size_t)s0 * D + hoff);
            uint2 vu1 = *(const uint2*)(Vb + (size_t)s1 * D + hoff);
            uint2 vu2 = *(const uint2*)(Vb + (size_t)s2 * D + hoff);
            uint2 vu3 = *(const uint2*)(Vb + (size_t)s3 * D + hoff);
            float p0, p1, p2, p3;
            DOTQ(p0, r0, ku0);
            DOTQ(p1, r1, ku1);
            DOTQ(p2, r2, ku2);
            DOTQ(p3, r3, ku3);
            // 4 independent shfl-reduce chains (pipelined by scheduler)
            p0 += __shfl_xor(p0, 1); p1 += __shfl_xor(p1, 1);
            p2 += __shfl_xor(p2, 1); p3 += __shfl_xor(p3, 1);
            p0 += __shfl_xor(p0, 2); p1 += __shfl_xor(p1, 2);
            p2 += __shfl_xor(p2, 2); p3 += __shfl_xor(p3, 2);
            p0 += __shfl_xor(p0, 4); p1 += __shfl_xor(p1, 4);
            p2 += __shfl_xor(p2, 4); p3 += __shfl_xor(p3, 4);
            float ex0 = __expf(p0), ex1 = __expf(p1);
            float ex2 = __expf(p2), ex3 = __expf(p3);
            ACCE(r0, ex0, vu0);
            if (mc > 1) { ACCE(r1, ex1, vu1); }
            if (mc > 2) { ACCE(r2, ex2, vu2); }
            if (mc > 3) { ACCE(r3, ex3, vu3); }
        }
    }

    // ---- phase C: normalize + per-r message transform ----
    float macc[4] = {0.f, 0.f, 0.f, 0.f};
    #pragma unroll
    for (int r = 0; r < N_R; r++) {
        if (bnd[r] >= bnd[r + 1]) continue;
        float invd = 1.f / den[r];
        float4 uw = {ua[r][0] * invd, ua[r][1] * invd, ua[r][2] * invd, ua[r][3] * invd};
        __builtin_amdgcn_wave_barrier();
        *(float4*)&Uld[wave][h][fo] = uw;                     // wave-private scratch
        __builtin_amdgcn_wave_barrier();
        float Uv[32];
        #pragma unroll
        for (int i = 0; i < 8; i++)
            *(float4*)&Uv[4 * i] = *(const float4*)&Uld[wave][h][4 * i];
        const u16* mp = Mtb + ((size_t)(r * N_H + h) * DKD + fo) * DKD;
        #pragma unroll
        for (int j = 0; j < 4; j++) {
            const uint4* mr = (const uint4*)(mp + j * DKD);
            macc[j] += dot8f(mr[0], Uv) + dot8f(mr[1], Uv + 8)
                     + dot8f(mr[2], Uv + 16) + dot8f(mr[3], Uv + 24);
        }
        __builtin_amdgcn_wave_barrier();
    }

    float invp = (np > 0) ? 1.f / (float)np : 1.f;
    ushort4 o;
    o.x = f2bf(macc[0] * invp); o.y = f2bf(macc[1] * invp);
    o.z = f2bf(macc[2] * invp); o.w = f2bf(macc[3] * invp);
    *(ushort4*)(QTb + (size_t)n * D + hoff) = o;
}

// ---------------- typed output linear + sigmoid-skip blend (MFMA) ----------------
__global__ __launch_bounds__(256) void k_out(
    const u16* __restrict__ TBF, const float* __restrict__ x,
    const int* __restrict__ order, const int* __restrict__ off, const int* __restrict__ toff,
    const u16* __restrict__ Wab, const float* __restrict__ ba,
    const float* __restrict__ skip, float* __restrict__ out) {
    __shared__ __align__(16) u16 xs[TM][D + 8];
    int b = blockIdx.x;
    int t = -1;
    #pragma unroll
    for (int i = 0; i < N_T; i++)
        if (b >= toff[i] && b < toff[i + 1]) t = i;
    if (t < 0) return;
    int nodeBase = off[t] + (b - toff[t]) * TM;
    int count = min(TM, off[t + 1] - nodeBase);
    int tid = threadIdx.x;

    for (int j = tid; j < TM * 32; j += 256) {
        int row = j >> 5, ch = j & 31;
        ushort4 z = {0, 0, 0, 0};
        if (row < count) {
            int g = order[nodeBase + row];
            const ushort4* p = (const ushort4*)(TBF + (size_t)g * D + ch * 8);
            *(ushort4*)&xs[row][ch * 8] = p[0];
            *(ushort4*)&xs[row][ch * 8 + 4] = p[1];
        } else {
            *(ushort4*)&xs[row][ch * 8] = z;
            *(ushort4*)&xs[row][ch * 8 + 4] = z;
        }
    }
    __syncthreads();

    int lane = tid & 63, wave = tid >> 6;
    int m = lane & 15, quad = lane >> 4;
    v8bf a[8];
    #pragma unroll
    for (int ks = 0; ks < 8; ks++)
        a[ks] = *(const v8bf*)&xs[wave * 16 + m][ks * 32 + quad * 8];

    int grow[4]; bool vrow[4];
    #pragma unroll
    for (int r = 0; r < 4; r++) {
        int rowi = wave * 16 + quad * 4 + r;
        vrow[r] = (rowi < count);
        grow[r] = vrow[r] ? order[nodeBase + rowi] : 0;
    }

    float sv = skip[t];
    float alpha = 1.f / (1.f + __expf(-sv));
    float beta = 1.f - alpha;
    const u16* W = Wab + (size_t)t * D * D;

    for (int dt = 0; dt < 16; dt++) {
        int dcol = dt * 16 + m;
        v4f acc = {0.f, 0.f, 0.f, 0.f};
        #pragma unroll
        for (int ks = 0; ks < 8; ks++) {
            v8bf bf = *(const v8bf*)(W + (size_t)dcol * D + ks * 32 + quad * 8);
            acc = __builtin_amdgcn_mfma_f32_16x16x32_bf16(a[ks], bf, acc, 0, 0, 0);
        }
        float bias = ba[t * D + dcol];
        #pragma unroll
        for (int r = 0; r < 4; r++) {
            if (vrow[r]) {
                size_t o = (size_t)grow[r] * D + dcol;
                out[o] = alpha * (acc[r] + bias) + beta * x[o];
            }
        }
    }
}

// ---------------- launch ----------------
extern "C" void kernel_launch(void* const* d_in, const int* in_sizes, int n_in,
                              void* d_out, int out_size, void* d_ws, size_t ws_size,
                              hipStream_t stream) {
    const float* x       = (const float*)d_in[0];
    const int* node_type = (const int*)d_in[1];
    const int* src       = (const int*)d_in[2];
    const int* dst       = (const int*)d_in[3];
    const int* etype     = (const int*)d_in[4];
    const float* Wk = (const float*)d_in[5];
    const float* bk = (const float*)d_in[6];
    const float* Wq = (const float*)d_in[7];
    const float* bq = (const float*)d_in[8];
    const float* Wv = (const float*)d_in[9];
    const float* bv = (const float*)d_in[10];
    const float* Wa = (const float*)d_in[11];
    const float* ba = (const float*)d_in[12];
    const float* rel_pri = (const float*)d_in[13];
    const float* rel_att = (const float*)d_in[14];
    const float* rel_msg = (const float*)d_in[15];
    const float* skip    = (const float*)d_in[16];
    float* out = (float*)d_out;
    char* ws = (char*)d_ws;

    // ws (~79.7 MB): Kb | Qb | Vb (bf16 node tensors), bf16 weights, order,
    // counters. TBF aliases Qb (per-row read-then-write by same wave).
    const size_t SZH = (size_t)N_NODES * D * 2;          // 25.6 MB
    const size_t WSZ = (size_t)N_T * D * D;              // 262144 elems
    const size_t RSZ = (size_t)N_R * N_H * DKD * DKD;    // 65536 elems
    u16* Kb  = (u16*)(ws);
    u16* Qb  = (u16*)(ws + SZH);
    u16* Vb  = (u16*)(ws + 2 * SZH);
    u16* TBF = Qb;                              // aliases Qb
    u16* Wkb = (u16*)(ws + 3 * SZH);
    u16* Wqb = Wkb + WSZ;
    u16* Wvb = Wqb + WSZ;
    u16* Wab = Wvb + WSZ;
    u16* Ab  = Wab + WSZ;
    u16* Mtb = Ab + RSZ;
    int* order = (int*)(Mtb + RSZ);
    int* small = order + N_NODES;
    int* cnt  = small;        // 4
    int* cur  = small + 4;    // 4
    int* offp = small + 8;    // 5
    int* toffp= small + 13;   // 5

    // d_out as scratch (all dead before k_out rewrites it):
    //   rowptr_seg[S+1] | cnt_seg[S] | cur_seg[S] | esrc[E] | bsum — ~6.4 MB of 51.2 MB
    char* ob = (char*)d_out;
    int* rowptr_seg = (int*)ob;                          // 400001
    int* cnt_seg    = rowptr_seg + (N_SEG + 16);         // 400000
    int* cur_seg    = cnt_seg + N_SEG;                   // 400000 (contiguous w/ cnt)
    int* esrc       = cur_seg + N_SEG;                   // 400000
    int* bsum       = esrc + N_EDGES;                    // 391 (+pad)

    hipMemsetAsync(small, 0, 8 * sizeof(int), stream);
    hipMemsetAsync(cnt_seg, 0, 2 * (size_t)N_SEG * sizeof(int), stream);

    // weight conversions
    k_cvt4<<<(WSZ / 4 + 255) / 256, 256, 0, stream>>>((const float4*)Wk, (ushort4*)Wkb, WSZ / 4);
    k_cvt4<<<(WSZ / 4 + 255) / 256, 256, 0, stream>>>((const float4*)Wq, (ushort4*)Wqb, WSZ / 4);
    k_cvt4<<<(WSZ / 4 + 255) / 256, 256, 0, stream>>>((const float4*)Wv, (ushort4*)Wvb, WSZ / 4);
    k_cvt4<<<(WSZ / 4 + 255) / 256, 256, 0, stream>>>((const float4*)Wa, (ushort4*)Wab, WSZ / 4);
    k_cvt4<<<(RSZ / 4 + 255) / 256, 256, 0, stream>>>((const float4*)rel_att, (ushort4*)Ab, RSZ / 4);
    k_cvt_t<<<(RSZ + 255) / 256, 256, 0, stream>>>(rel_msg, Mtb);

    // node-type buckets
    k_hist<<<(N_NODES + 255) / 256, 256, 0, stream>>>(node_type, cnt);
    k_scan<<<1, 1, 0, stream>>>(cnt, offp, toffp);
    k_scatter<<<(N_NODES + 255) / 256, 256, 0, stream>>>(node_type, offp, cur, order);

    // segment CSR (dst*R + etype)
    const int NB = (N_SEG + 1023) / 1024;                // 391
    k_hist_seg<<<(N_EDGES + 255) / 256, 256, 0, stream>>>(dst, etype, cnt_seg);
    k_scan_l1<<<NB, 1024, 0, stream>>>(cnt_seg, rowptr_seg, bsum);
    k_scan_l2<<<1, 512, 0, stream>>>(bsum, NB);
    k_scan_l3<<<(N_SEG + 1 + 255) / 256, 256, 0, stream>>>(rowptr_seg, bsum);
    k_scatter_seg<<<(N_EDGES + 255) / 256, 256, 0, stream>>>(src, dst, etype,
                                                             rowptr_seg, cur_seg, esrc);

    k_proj<<<PROJ_BLOCKS, 256, 0, stream>>>(x, order, offp, toffp,
                                            Wkb, bk, Wqb, bq, Wvb, bv, Kb, Qb, Vb);

    k_fused<<<(N_NODES + 3) / 4, 256, 0, stream>>>(Kb, Qb, Vb, rowptr_seg, esrc,
                                                   Ab, Mtb, rel_pri);

    k_out<<<PROJ_BLOCKS, 256, 0, stream>>>(TBF, x, order, offp, toffp,
                                           Wab, ba, skip, out);
}